// Round 11
// baseline (89.262 us; speedup 1.0000x reference)
//
#include <hip/hip_runtime.h>
#include <hip/hip_fp16.h>

// Raymarcher: R=16384 rays, 64 steps, K=32 prims, template (32,4,16,16,16) f32.
// Round 11: 1 ray/wave, quad-substep packing. Lanes 0-31 handle substeps
// 4j,4j+1; lanes 32-63 handle 4j+2,4j+3 (2 independent evals per lane per
// iteration) -> 16 iterations, double load ILP, half the per-iteration
// reduce/branch overhead of r10. Exact 4-substep alpha chain from one paired
// half-reduce + xor32 exchange. f-clamps dropped (g in [0,15] single-rounded
// => f in [0,1] automatically). fp16 channel-last template, 16B x-pair loads.

namespace {

constexpr float kDT  = 1.0f / 64.0f;
constexpr int   kVox = 32 * 4096;   // (k,z,y,x) voxel count

struct H4 { __half2 lo, hi; };                                       // voxel, 8 B
struct __attribute__((aligned(8))) H4x2 { __half2 l0, h0, l1, h1; }; // (x,x+1), 16 B

// ---- pre-pass: (k,c,z,y,x) f32 -> (k,z,y,x,c) fp16 ----
__global__ __launch_bounds__(256) void transpose_tmpl_h(
    const float* __restrict__ tmpl, H4* __restrict__ wsH)
{
    const int idx = blockIdx.x * 256 + threadIdx.x;     // < 131072
    const int k   = idx >> 12;
    const int rem = idx & 4095;
    const float* src = tmpl + k * 16384 + rem;
    H4 v;
    v.lo = __floats2half2_rn(src[0],    src[4096]);
    v.hi = __floats2half2_rn(src[8192], src[12288]);
    wsH[idx] = v;
}

__device__ __forceinline__ __half2 lerp2(__half2 a, __half2 b, __half2 f) {
    return __hfma2(f, __hsub2(b, a), a);
}

// One trilinear eval at local coords y (|y|<=1 guaranteed by caller).
__device__ __forceinline__ float4 trilerp(const H4* __restrict__ tbase,
                                          float y0, float y1, float y2)
{
    const float gz = fmaf(y0, 7.5f, 7.5f);   // [0,15], single-rounded
    const float gy = fmaf(y1, 7.5f, 7.5f);
    const float gx = fmaf(y2, 7.5f, 7.5f);
    const int iz = min((int)gz, 14);          // trunc == floor for g>=0
    const int iy = min((int)gy, 14);
    const int ix = min((int)gx, 14);
    const float fz = gz - (float)iz;          // in [0,1] automatically
    const float fy = gy - (float)iy;
    const float fx = gx - (float)ix;

    const H4* tp = tbase + (iz * 256 + iy * 16 + ix);
    const H4x2 p00 = *(const H4x2*)(tp + 0);
    const H4x2 p01 = *(const H4x2*)(tp + 16);
    const H4x2 p10 = *(const H4x2*)(tp + 256);
    const H4x2 p11 = *(const H4x2*)(tp + 272);

    const __half2 hz = __float2half2_rn(fz);
    const __half2 hy = __float2half2_rn(fy);
    const __half2 hx = __float2half2_rn(fx);

    const __half2 q0l0 = lerp2(p00.l0, p10.l0, hz);
    const __half2 q0h0 = lerp2(p00.h0, p10.h0, hz);
    const __half2 q0l1 = lerp2(p00.l1, p10.l1, hz);
    const __half2 q0h1 = lerp2(p00.h1, p10.h1, hz);
    const __half2 q1l0 = lerp2(p01.l0, p11.l0, hz);
    const __half2 q1h0 = lerp2(p01.h0, p11.h0, hz);
    const __half2 q1l1 = lerp2(p01.l1, p11.l1, hz);
    const __half2 q1h1 = lerp2(p01.h1, p11.h1, hz);

    const __half2 ul0 = lerp2(q0l0, q1l0, hy);
    const __half2 uh0 = lerp2(q0h0, q1h0, hy);
    const __half2 ul1 = lerp2(q0l1, q1l1, hy);
    const __half2 uh1 = lerp2(q0h1, q1h1, hy);

    const __half2 vl = lerp2(ul0, ul1, hx);
    const __half2 vh = lerp2(uh0, uh1, hx);

    const float2 fLo = __half22float2(vl);
    const float2 fHi = __half22float2(vh);
    return make_float4(fLo.x, fLo.y, fHi.x, fHi.y);
}

__global__ __launch_bounds__(256) void raymarch10(
    const float* __restrict__ raypos,
    const float* __restrict__ raydir,
    const float* __restrict__ tminmax,
    const float* __restrict__ primpos,
    const float* __restrict__ primrot,
    const float* __restrict__ primscale,
    const H4* __restrict__ wsH,
    float* __restrict__ out,
    int R)
{
    const int lane   = threadIdx.x & 63;
    const int wid    = threadIdx.x >> 6;        // wave 0..3
    const int k      = lane & 31;               // prim owned by this lane
    const int parity = lane >> 5;               // 0: substeps 4j,4j+1; 1: 4j+2,4j+3
    const int ray    = blockIdx.x * 4 + wid;    // one ray per wave

    const float rpx = raypos[ray * 3 + 0];
    const float rpy = raypos[ray * 3 + 1];
    const float rpz = raypos[ray * 3 + 2];
    const float rdx = raydir[ray * 3 + 0];
    const float rdy = raydir[ray * 3 + 1];
    const float rdz = raydir[ray * 3 + 2];
    const float tmin = tminmax[ray * 2 + 0];
    const float tmax = tminmax[ray * 2 + 1];

    // Fold prim k into affine y_i(t) = A_i + D_i*t (verified r1-r10 math).
    float A0, A1, A2, D0, D1, D2;
    {
        const float ox = rpx - primpos[k * 3 + 0];
        const float oy = rpy - primpos[k * 3 + 1];
        const float oz = rpz - primpos[k * 3 + 2];
        const float s0 = primscale[k * 3 + 0];
        const float s1 = primscale[k * 3 + 1];
        const float s2 = primscale[k * 3 + 2];
        const float* rk = primrot + k * 9;
        A0 = (rk[0] * ox + rk[1] * oy + rk[2] * oz) * s0;
        D0 = (rk[0] * rdx + rk[1] * rdy + rk[2] * rdz) * s0;
        A1 = (rk[3] * ox + rk[4] * oy + rk[5] * oz) * s1;
        D1 = (rk[3] * rdx + rk[4] * rdy + rk[5] * rdz) * s1;
        A2 = (rk[6] * ox + rk[7] * oy + rk[8] * oz) * s2;
        D2 = (rk[6] * rdx + rk[7] * rdy + rk[8] * rdz) * s2;
    }

    const H4* __restrict__ tbase = wsH + k * 4096;

    float alpha = 0.f;                      // wave-uniform
    float r0 = 0.f, r1 = 0.f, r2 = 0.f;     // per-lane rgb partials

    for (int j = 0; j < 16; ++j) {
        const float tq = fmaf((float)(4 * j), kDT, tmin);      // quad base
        if (tq >= tmax || alpha >= 1.0f) break;                // uniform branch

        // lane's two substeps: sA = 4j + 2*parity, sB = sA + 1
        const float tA = fmaf((float)(4 * j + 2 * parity),     kDT, tmin);
        const float tB = fmaf((float)(4 * j + 2 * parity + 1), kDT, tmin);

        const float yA0 = fmaf(D0, tA, A0);
        const float yA1 = fmaf(D1, tA, A1);
        const float yA2 = fmaf(D2, tA, A2);
        const float yB0 = fmaf(D0, tB, A0);
        const float yB1 = fmaf(D1, tB, A1);
        const float yB2 = fmaf(D2, tB, A2);

        const bool inA = (tA < tmax) && fabsf(yA0) <= 1.0f
                      && fabsf(yA1) <= 1.0f && fabsf(yA2) <= 1.0f;
        const bool inB = (tB < tmax) && fabsf(yB0) <= 1.0f
                      && fabsf(yB1) <= 1.0f && fabsf(yB2) <= 1.0f;
        if (__ballot(inA || inB) == 0ull) continue;

        float4 sA = make_float4(0.f, 0.f, 0.f, 0.f);
        float4 sB = make_float4(0.f, 0.f, 0.f, 0.f);
        if (inA) sA = trilerp(tbase, yA0, yA1, yA2);
        if (inB) sB = trilerp(tbase, yB0, yB1, yB2);

        // paired half-local reduce of the two alpha channels
        float u = sA.w, v = sB.w;
        #pragma unroll
        for (int m = 1; m < 32; m <<= 1) {
            u += __shfl_xor(u, m);
            v += __shfl_xor(v, m);
        }
        const float uo = __shfl_xor(u, 32);   // other half's pair
        const float vo = __shfl_xor(v, 32);
        // substep totals 0..3 of this quad
        const float T0 = parity ? uo : u;
        const float T1 = parity ? vo : v;
        const float T2 = parity ? u  : uo;
        const float T3 = parity ? v  : vo;

        // exact 4-substep alpha chain (totals >= 0 => clip == min)
        const float t1 = fmaf((float)(4 * j + 1), kDT, tmin);
        const float t2 = fmaf((float)(4 * j + 2), kDT, tmin);
        const float t3 = fmaf((float)(4 * j + 3), kDT, tmin);
        const float a0 = T0 * kDT;                       // tq < tmax held
        const float a1 = (t1 < tmax) ? T1 * kDT : 0.0f;
        const float a2 = (t2 < tmax) ? T2 * kDT : 0.0f;
        const float a3 = (t3 < tmax) ? T3 * kDT : 0.0f;
        const float n0 = fminf(alpha + a0, 1.0f); const float c0 = n0 - alpha;
        const float n1 = fminf(n0 + a1, 1.0f);    const float c1 = n1 - n0;
        const float n2 = fminf(n1 + a2, 1.0f);    const float c2 = n2 - n1;
        const float n3 = fminf(n2 + a3, 1.0f);    const float c3 = n3 - n2;
        alpha = n3;

        const float cA = parity ? c2 : c0;
        const float cB = parity ? c3 : c1;
        r0 = fmaf(sA.x, cA, fmaf(sB.x, cB, r0));
        r1 = fmaf(sA.y, cA, fmaf(sB.y, cB, r1));
        r2 = fmaf(sA.z, cA, fmaf(sB.z, cB, r2));
    }

    // full-wave rgb reduce
    #pragma unroll
    for (int m = 1; m < 64; m <<= 1) {
        r0 += __shfl_xor(r0, m);
        r1 += __shfl_xor(r1, m);
        r2 += __shfl_xor(r2, m);
    }

    if (lane == 0) {
        out[0 * R + ray] = r0;
        out[1 * R + ray] = r1;
        out[2 * R + ray] = r2;
        out[3 * R + ray] = alpha;
        out[4 * R + ray] = r0;
        out[5 * R + ray] = r1;
        out[6 * R + ray] = r2;
        out[7 * R + ray] = alpha;
    }
}

// ---- fallback (r6-style, original f32 template) for tiny ws ----
__global__ __launch_bounds__(256) void raymarch_fb(
    const float* __restrict__ raypos, const float* __restrict__ raydir,
    const float* __restrict__ tminmax, const float* __restrict__ primpos,
    const float* __restrict__ primrot, const float* __restrict__ primscale,
    const float* __restrict__ tmpl, float* __restrict__ out, int R)
{
    const int lane = threadIdx.x & 63;
    const int wid  = threadIdx.x >> 6;
    const int k    = lane & 31;
    const int half = lane >> 5;
    const int ray  = blockIdx.x * 8 + wid * 2 + half;

    const float rpx = raypos[ray*3+0], rpy = raypos[ray*3+1], rpz = raypos[ray*3+2];
    const float rdx = raydir[ray*3+0], rdy = raydir[ray*3+1], rdz = raydir[ray*3+2];
    const float tmin = tminmax[ray*2+0], tmax = tminmax[ray*2+1];

    float A0,A1,A2,D0,D1,D2;
    {
        const float ox = rpx - primpos[k*3+0], oy = rpy - primpos[k*3+1], oz = rpz - primpos[k*3+2];
        const float s0 = primscale[k*3+0], s1 = primscale[k*3+1], s2 = primscale[k*3+2];
        const float* rk = primrot + k*9;
        A0 = (rk[0]*ox+rk[1]*oy+rk[2]*oz)*s0; D0 = (rk[0]*rdx+rk[1]*rdy+rk[2]*rdz)*s0;
        A1 = (rk[3]*ox+rk[4]*oy+rk[5]*oz)*s1; D1 = (rk[3]*rdx+rk[4]*rdy+rk[5]*rdz)*s1;
        A2 = (rk[6]*ox+rk[7]*oy+rk[8]*oz)*s2; D2 = (rk[6]*rdx+rk[7]*rdy+rk[8]*rdz)*s2;
    }
    float alpha = 0.f, r0 = 0.f, r1 = 0.f, r2 = 0.f;
    for (int i = 0; i < 64; ++i) {
        const float t = fmaf((float)i, kDT, tmin);
        const bool live = (t < tmax) && (alpha < 1.0f);
        if (__ballot(live) == 0ull) break;
        const float y0 = fmaf(D0,t,A0), y1 = fmaf(D1,t,A1), y2 = fmaf(D2,t,A2);
        const bool inside = live && fabsf(y0)<=1.f && fabsf(y1)<=1.f && fabsf(y2)<=1.f;
        if (__ballot(inside) == 0ull) continue;
        float s0=0.f,s1=0.f,s2=0.f,s3=0.f;
        if (inside) {
            const float gz=(y0+1.f)*7.5f, gy=(y1+1.f)*7.5f, gx=(y2+1.f)*7.5f;
            const int iz=(int)fminf(floorf(gz),14.f), iy=(int)fminf(floorf(gy),14.f), ix=(int)fminf(floorf(gx),14.f);
            const float fz=fminf(gz-(float)iz,1.f), fy=fminf(gy-(float)iy,1.f), fx=fminf(gx-(float)ix,1.f);
            const float oz_=1.f-fz, oy_=1.f-fy, ox_=1.f-fx;
            const float w000=oz_*oy_*ox_, w001=oz_*oy_*fx, w010=oz_*fy*ox_, w011=oz_*fy*fx;
            const float w100=fz*oy_*ox_, w101=fz*oy_*fx, w110=fz*fy*ox_, w111=fz*fy*fx;
            const float* tp = tmpl + k*16384 + iz*256 + iy*16 + ix;
            float acc[4];
            #pragma unroll
            for (int c = 0; c < 4; ++c) {
                const float* tc = tp + c*4096;
                acc[c] = w000*tc[0]+w001*tc[1]+w010*tc[16]+w011*tc[17]
                       + w100*tc[256]+w101*tc[257]+w110*tc[272]+w111*tc[273];
            }
            s0=acc[0]; s1=acc[1]; s2=acc[2]; s3=acc[3];
        }
        float tot3 = s3;
        #pragma unroll
        for (int m = 1; m < 32; m <<= 1) tot3 += __shfl_xor(tot3, m);
        const float na = fminf(fmaf(tot3, kDT, alpha), 1.0f);
        const float contrib = na - alpha;
        alpha = na;
        r0 = fmaf(s0, contrib, r0); r1 = fmaf(s1, contrib, r1); r2 = fmaf(s2, contrib, r2);
    }
    #pragma unroll
    for (int m = 1; m < 32; m <<= 1) {
        r0 += __shfl_xor(r0, m); r1 += __shfl_xor(r1, m); r2 += __shfl_xor(r2, m);
    }
    if (k == 0) {
        out[0*R+ray]=r0; out[1*R+ray]=r1; out[2*R+ray]=r2; out[3*R+ray]=alpha;
        out[4*R+ray]=r0; out[5*R+ray]=r1; out[6*R+ray]=r2; out[7*R+ray]=alpha;
    }
}

} // namespace

extern "C" void kernel_launch(void* const* d_in, const int* in_sizes, int n_in,
                              void* d_out, int out_size, void* d_ws, size_t ws_size,
                              hipStream_t stream) {
    const float* raypos    = (const float*)d_in[0];
    const float* raydir    = (const float*)d_in[1];
    const float* tminmax   = (const float*)d_in[2];
    const float* primpos   = (const float*)d_in[3];
    const float* primrot   = (const float*)d_in[4];
    const float* primscale = (const float*)d_in[5];
    const float* tmpl      = (const float*)d_in[6];
    float* out = (float*)d_out;

    const int R = in_sizes[0] / 3;   // 16384
    const size_t needH = (size_t)kVox * sizeof(H4);   // 1 MiB

    if (ws_size >= needH) {
        H4* wsH = (H4*)d_ws;
        transpose_tmpl_h<<<dim3(kVox / 256), dim3(256), 0, stream>>>(tmpl, wsH);
        raymarch10<<<dim3(R / 4), dim3(256), 0, stream>>>(
            raypos, raydir, tminmax, primpos, primrot, primscale, wsH, out, R);
    } else {
        raymarch_fb<<<dim3(R / 8), dim3(256), 0, stream>>>(
            raypos, raydir, tminmax, primpos, primrot, primscale, tmpl, out, R);
    }
}